// Round 21
// baseline (2228.104 us; speedup 1.0000x reference)
//
#include <hip/hip_runtime.h>
#include <hip/hip_bf16.h>

#define NP   16384
#define KNN  32
#define HDIM 128
#define ODIM 64

typedef __attribute__((ext_vector_type(8))) short bf16x8;
typedef __attribute__((ext_vector_type(4))) float f32x4;

#define BAR_LGKM() do { \
    asm volatile("s_waitcnt lgkmcnt(0)" ::: "memory"); \
    __builtin_amdgcn_sched_barrier(0); \
    __builtin_amdgcn_s_barrier(); \
    __builtin_amdgcn_sched_barrier(0); } while (0)
#define BAR_ALL() do { \
    asm volatile("s_waitcnt vmcnt(0) lgkmcnt(0)" ::: "memory"); \
    __builtin_amdgcn_sched_barrier(0); \
    __builtin_amdgcn_s_barrier(); \
    __builtin_amdgcn_sched_barrier(0); } while (0)

// ---------------- split fp32 -> bf16 (hi, lo) planes ----------------
__global__ __launch_bounds__(256)
void split_kernel(const float* __restrict__ X, unsigned short* __restrict__ hi,
                  unsigned short* __restrict__ lo, int n4) {
    const int i = blockIdx.x * 256 + threadIdx.x;
    if (i >= n4) return;
    const float4 v = reinterpret_cast<const float4*>(X)[i];
    const float vv[4] = {v.x, v.y, v.z, v.w};
    ushort4 h, l;
    unsigned short* hp = &h.x;
    unsigned short* lp = &l.x;
    #pragma unroll
    for (int c = 0; c < 4; ++c) {
        __hip_bfloat16 hb = __float2bfloat16(vv[c]);           // RNE
        const float hf = __bfloat162float(hb);
        __hip_bfloat16 lb = __float2bfloat16(vv[c] - hf);
        hp[c] = *reinterpret_cast<unsigned short*>(&hb);
        lp[c] = *reinterpret_cast<unsigned short*>(&lb);
    }
    reinterpret_cast<ushort4*>(hi)[i] = h;
    reinterpret_cast<ushort4*>(lo)[i] = l;
}

__global__ __launch_bounds__(256)
void wsplit_kernel(const float* __restrict__ W, unsigned short* __restrict__ hi,
                   unsigned short* __restrict__ lo, int Dd) {
    const int i = blockIdx.x * 256 + threadIdx.x;
    if (i >= HDIM * Dd) return;
    const int hh = i / Dd, d = i % Dd;
    const float v = W[(size_t)hh * (2 * Dd) + d];
    __hip_bfloat16 hb = __float2bfloat16(v);
    const float hf = __bfloat162float(hb);
    __hip_bfloat16 lb = __float2bfloat16(v - hf);
    hi[i] = *reinterpret_cast<unsigned short*>(&hb);
    lo[i] = *reinterpret_cast<unsigned short*>(&lb);
}

// ---------------- squared norms ----------------
template<int D>
__global__ __launch_bounds__(256)
void sq_kernel(const float* __restrict__ X, float* __restrict__ sq) {
    const int lane = threadIdx.x & 63;
    const int row  = blockIdx.x * 4 + (threadIdx.x >> 6);
    float s = 0.f;
    #pragma unroll
    for (int d = lane; d < D; d += 64) {
        const float v = X[(size_t)row * D + d];
        s = fmaf(v, v, s);
    }
    #pragma unroll
    for (int off = 32; off; off >>= 1) s += __shfl_down(s, off);
    if (lane == 0) sq[row] = s;
}

// ---------------- top-32 neighbors: MFMA scores + sorted register top-k ----
// TI=32 (2 A-rowblocks resident; B-frag reads amortized 2x), JC=128, 8 waves.
// Single xjB; 16-row score buffer reused across 2 phases (4 lgkm barriers);
// staging issued after phase-0 barrier, drained at tile-end vmcnt barrier.
template<int D>
__global__ __launch_bounds__(512, 4)
void topk_kernel(const unsigned short* __restrict__ Xhi,
                 const unsigned short* __restrict__ Xlo,
                 const float* __restrict__ sq, int* __restrict__ topIdx) {
    constexpr int TI = 32, JC = 128, SS = JC + 1;
    constexpr int NT = NP / JC;
    constexpr int KQ = D / 8;
    constexpr int KS = D / 32;
    constexpr int PLSLOT = JC * KQ;
    constexpr int CALLS = 2 * PLSLOT / 512;
    __shared__ __align__(16) unsigned short xjB[2 * PLSLOT * 8];  // hi | lo
    __shared__ float scoresR[16 * SS];   // one rowblock at a time, stride 129

    const int t = threadIdx.x;
    const int lane = t & 63;
    const int waveU = __builtin_amdgcn_readfirstlane(t >> 6);
    const int rowBase = blockIdx.x * TI;
    const int l15 = lane & 15, l4 = lane >> 4;
    const float INF = __builtin_inff();
    const int jcol = 16 * waveU + l15;

    bf16x8 Ahi[2][KS], Alo[2][KS];
    #pragma unroll
    for (int rb = 0; rb < 2; ++rb)
        #pragma unroll
        for (int s = 0; s < KS; ++s) {
            const size_t off = (size_t)(rowBase + rb * 16 + l15) * D + 32 * s + 8 * l4;
            Ahi[rb][s] = *reinterpret_cast<const bf16x8*>(Xhi + off);
            Alo[rb][s] = *reinterpret_cast<const bf16x8*>(Xlo + off);
        }

    float tv[4]; int tidx[4]; float minv[4];   // [phase*2 + r]
    #pragma unroll
    for (int r = 0; r < 4; ++r) { tv[r] = -INF; tidx[r] = 0x7fffffff; minv[r] = -INF; }

    auto stageTile = [&](int jb) {
        #pragma unroll
        for (int c = 0; c < CALLS; ++c) {
            const int slotBase = (waveU * CALLS + c) * 64;
            const int sl = slotBase + lane;
            const int pl = sl / PLSLOT;
            const int ps = sl % PLSLOT;
            const int j  = ps / KQ;
            const int kq = (ps % KQ) ^ (j & (KQ - 1));
            const unsigned short* src =
                (pl ? Xlo : Xhi) + (size_t)(jb + j) * D + 8 * kq;
            __builtin_amdgcn_global_load_lds(
                (const __attribute__((address_space(1))) void*)src,
                (__attribute__((address_space(3))) void*)&xjB[(size_t)slotBase * 8],
                16, 0, 0);
        }
    };

#define SCAN_PHASE(BASE, JB) do {                                              \
    _Pragma("unroll")                                                          \
    for (int h = 0; h < 2; ++h) {                                              \
        float sv[2];                                                           \
        unsigned long long m[2];                                               \
        _Pragma("unroll")                                                      \
        for (int r = 0; r < 2; ++r) {                                          \
            sv[r] = scoresR[(2 * waveU + r) * SS + h * 64 + lane]              \
                  - (h ? sub1 : sub0);                                         \
            m[r] = __ballot(sv[r] > minv[(BASE) + r]);                         \
        }                                                                      \
        while (m[0] | m[1]) {                                                  \
            _Pragma("unroll")                                                  \
            for (int r = 0; r < 2; ++r) {                                      \
                if (m[r]) {                                                    \
                    const int l = __builtin_ctzll(m[r]);                       \
                    m[r] &= m[r] - 1;                                          \
                    const float cv = __int_as_float(                           \
                        __builtin_amdgcn_readlane(__float_as_int(sv[r]), l));  \
                    const int cj = (JB) + h * 64 + l;                          \
                    const float upv = __shfl_up(tv[(BASE) + r], 1);            \
                    const int   upi = __shfl_up(tidx[(BASE) + r], 1);          \
                    const bool ge = (lane < KNN) && (tv[(BASE) + r] >= cv);    \
                    const int pp = __popcll(__ballot(ge));                     \
                    if (lane == pp) { tv[(BASE)+r] = cv;  tidx[(BASE)+r] = cj; } \
                    else if (lane > pp && lane < KNN)                          \
                                    { tv[(BASE)+r] = upv; tidx[(BASE)+r] = upi; } \
                }                                                              \
            }                                                                  \
        }                                                                      \
        minv[(BASE) + 0] = __shfl(tv[(BASE) + 0], KNN - 1);                    \
        minv[(BASE) + 1] = __shfl(tv[(BASE) + 1], KNN - 1);                    \
    } } while (0)

    stageTile(0);
    BAR_ALL();

    for (int it = 0; it < NT; ++it) {
        const int jb = it * JC;
        const float sub0 = 0.5f * sq[jb + lane];
        const float sub1 = 0.5f * sq[jb + 64 + lane];

        f32x4 C0a = {0,0,0,0}, C0b = {0,0,0,0};
        f32x4 C1a = {0,0,0,0}, C1b = {0,0,0,0};
        #pragma unroll
        for (int s = 0; s < KS; ++s) {
            const int kq = 4 * s + l4;
            const int slot = jcol * KQ + (kq ^ (jcol & (KQ - 1)));
            const bf16x8 Bh = *reinterpret_cast<const bf16x8*>(&xjB[(size_t)slot * 8]);
            const bf16x8 Bl = *reinterpret_cast<const bf16x8*>(&xjB[(size_t)(PLSLOT + slot) * 8]);
            C0a = __builtin_amdgcn_mfma_f32_16x16x32_bf16(Ahi[0][s], Bh, C0a, 0, 0, 0);
            C0b = __builtin_amdgcn_mfma_f32_16x16x32_bf16(Ahi[0][s], Bl, C0b, 0, 0, 0);
            C0b = __builtin_amdgcn_mfma_f32_16x16x32_bf16(Alo[0][s], Bh, C0b, 0, 0, 0);
            C1a = __builtin_amdgcn_mfma_f32_16x16x32_bf16(Ahi[1][s], Bh, C1a, 0, 0, 0);
            C1b = __builtin_amdgcn_mfma_f32_16x16x32_bf16(Ahi[1][s], Bl, C1b, 0, 0, 0);
            C1b = __builtin_amdgcn_mfma_f32_16x16x32_bf16(Alo[1][s], Bh, C1b, 0, 0, 0);
        }

        // phase 0: rowblock 0
        #pragma unroll
        for (int r = 0; r < 4; ++r)
            scoresR[(4 * l4 + r) * SS + jcol] = C0a[r] + C0b[r];
        BAR_LGKM();                       // xjB reads + RB0 scatter done
        if (it + 1 < NT) stageTile(jb + JC);
        SCAN_PHASE(0, jb);
        BAR_LGKM();                       // RB0 scan reads done

        // phase 1: rowblock 1
        #pragma unroll
        for (int r = 0; r < 4; ++r)
            scoresR[(4 * l4 + r) * SS + jcol] = C1a[r] + C1b[r];
        BAR_LGKM();                       // RB1 scatter visible
        SCAN_PHASE(2, jb);
        BAR_ALL();                        // staging landed + RB1 reads done
    }

    if (lane < KNN) {
        #pragma unroll
        for (int p = 0; p < 2; ++p)
            #pragma unroll
            for (int r = 0; r < 2; ++r)
                topIdx[(size_t)(rowBase + p * 16 + 2 * waveU + r) * KNN + lane]
                    = tidx[p * 2 + r];
    }
#undef SCAN_PHASE
}

// ---------------- gather + MLP (MFMA) + pool + out (unchanged from R19) ----
template<int D, int LAYER>
__global__ __launch_bounds__(512, 4)
void mlp_kernel(const float* __restrict__ X,
                const unsigned short* __restrict__ Xhi,
                const unsigned short* __restrict__ Xlo,
                const unsigned short* __restrict__ WAhi,
                const unsigned short* __restrict__ WAlo,
                const float* __restrict__ W, const float* __restrict__ W2,
                const int* __restrict__ topIdx, float* __restrict__ out) {
    constexpr int RPB = 2;
    constexpr int KS = D / 32;
    constexpr int W2C  = HDIM + D;
    constexpr int SPL2 = 4;
    constexpr int CL   = W2C / SPL2;
    __shared__ float AT[D * HDIM];
    __shared__ float xi[RPB][D];
    __shared__ float hself_s[RPB][HDIM];
    __shared__ float part[RPB][2][HDIM];
    __shared__ int   idx_s[RPB][KNN];

    const int t = threadIdx.x;
    const int lane = t & 63;
    const int waveU = __builtin_amdgcn_readfirstlane(t >> 6);
    const int rowBase = blockIdx.x * RPB;
    const int l15 = lane & 15, l4 = lane >> 4;

    if (t < RPB * D / 4) {
        const int i = t / (D / 4), dg = t % (D / 4);
        const float4 v = *reinterpret_cast<const float4*>(
            X + (size_t)(rowBase + i) * D + 4 * dg);
        xi[i][4 * dg + 0] = v.x; xi[i][4 * dg + 1] = v.y;
        xi[i][4 * dg + 2] = v.z; xi[i][4 * dg + 3] = v.w;
    }
    if (t < RPB * KNN)
        idx_s[t >> 5][t & 31] = topIdx[(size_t)(rowBase + (t >> 5)) * KNN + (t & 31)];
    bf16x8 Ahi[KS], Alo[KS];
    #pragma unroll
    for (int s = 0; s < KS; ++s) {
        const size_t off = (size_t)(waveU * 16 + l15) * D + 32 * s + 8 * l4;
        Ahi[s] = *reinterpret_cast<const bf16x8*>(WAhi + off);
        Alo[s] = *reinterpret_cast<const bf16x8*>(WAlo + off);
    }
    for (int e = t; e < HDIM * D / 4; e += 512) {
        const int hh = e % HDIM, dg = e / HDIM;
        const float4 v = *reinterpret_cast<const float4*>(
            W + (size_t)hh * (2 * D) + D + 4 * dg);          // B = W[:, D:2D]
        AT[(4 * dg + 0) * HDIM + hh] = v.x; AT[(4 * dg + 1) * HDIM + hh] = v.y;
        AT[(4 * dg + 2) * HDIM + hh] = v.z; AT[(4 * dg + 3) * HDIM + hh] = v.w;
    }
    __syncthreads();

    if (t < RPB * HDIM) {
        const int row = t >> 7, hh = t & 127;
        float s = 0.f;
        #pragma unroll 8
        for (int d = 0; d < D; ++d)
            s = fmaf(AT[d * HDIM + hh], xi[row][d], s);
        hself_s[row][hh] = s;
    }
    __syncthreads();

    #pragma unroll
    for (int a = 0; a < 4; ++a) {
        const int row = a >> 1, kT = a & 1;
        const int nIdx = idx_s[row][kT * 16 + l15];
        bf16x8 Bh[KS], Bl[KS];
        #pragma unroll
        for (int s = 0; s < KS; ++s) {
            const size_t off = (size_t)nIdx * D + 32 * s + 8 * l4;
            Bh[s] = *reinterpret_cast<const bf16x8*>(Xhi + off);
            Bl[s] = *reinterpret_cast<const bf16x8*>(Xlo + off);
        }
        f32x4 Ca = {0,0,0,0}, Cb = {0,0,0,0}, Cc = {0,0,0,0};
        #pragma unroll
        for (int s = 0; s < KS; ++s) {
            Ca = __builtin_amdgcn_mfma_f32_16x16x32_bf16(Ahi[s], Bh[s], Ca, 0, 0, 0);
            Cb = __builtin_amdgcn_mfma_f32_16x16x32_bf16(Ahi[s], Bl[s], Cb, 0, 0, 0);
            Cc = __builtin_amdgcn_mfma_f32_16x16x32_bf16(Alo[s], Bh[s], Cc, 0, 0, 0);
        }
        float ps[4];
        #pragma unroll
        for (int r = 0; r < 4; ++r) {
            const float h = (Ca[r] + Cb[r]) + Cc[r]
                          + hself_s[row][waveU * 16 + 4 * l4 + r];
            ps[r] = fminf(1.f, fmaxf(-1.f, h));
        }
        #pragma unroll
        for (int off = 1; off <= 8; off <<= 1)
            #pragma unroll
            for (int r = 0; r < 4; ++r)
                ps[r] += __shfl_xor(ps[r], off);
        if (l15 == 0)
            #pragma unroll
            for (int r = 0; r < 4; ++r)
                part[row][kT][waveU * 16 + 4 * l4 + r] = ps[r] * (1.f / KNN);
    }
    __syncthreads();

    {
        const int og   = t / SPL2;
        const int spl  = t % SPL2;
        const int orow = og >> 6, o = og & 63;
        const int c0   = spl * CL;
        float s = 0.f;
        for (int c4 = 0; c4 < CL / 4; ++c4) {
            const int c = c0 + 4 * c4;
            const float4 w = *reinterpret_cast<const float4*>(W2 + (size_t)o * W2C + c);
            float vs[4];
            if (c < HDIM) {
                const float4 q0 = *reinterpret_cast<const float4*>(&part[orow][0][c]);
                const float4 q1 = *reinterpret_cast<const float4*>(&part[orow][1][c]);
                vs[0] = q0.x + q1.x; vs[1] = q0.y + q1.y;
                vs[2] = q0.z + q1.z; vs[3] = q0.w + q1.w;
            } else {
                const float4 xv = *reinterpret_cast<const float4*>(&xi[orow][c - HDIM]);
                vs[0] = xv.x; vs[1] = xv.y; vs[2] = xv.z; vs[3] = xv.w;
            }
            const float wv[4] = {w.x, w.y, w.z, w.w};
            #pragma unroll
            for (int j = 0; j < 4; ++j)
                s = fmaf(vs[j], wv[j], s);
        }
        #pragma unroll
        for (int off = SPL2 / 2; off; off >>= 1) s += __shfl_down(s, off);
        if (spl == 0) {
            if (LAYER == 0)
                out[(size_t)(rowBase + orow) * 128 + 64 + o] = s;
            else
                out[(size_t)(rowBase + orow) * ODIM + o] = s;
        }
    }
    if (LAYER == 0 && t < RPB * 64) {
        const int orow = t >> 6, d = t & 63;
        out[(size_t)(rowBase + orow) * 128 + d] = xi[orow][d];
    }
}

extern "C" void kernel_launch(void* const* d_in, const int* in_sizes, int n_in,
                              void* d_out, int out_size, void* d_ws, size_t ws_size,
                              hipStream_t stream) {
    const float* x    = (const float*)d_in[0];
    const float* w0   = (const float*)d_in[1];
    const float* w2_0 = (const float*)d_in[2];
    const float* w1   = (const float*)d_in[3];
    const float* w2_1 = (const float*)d_in[4];
    float* out = (float*)d_out;

    char* ws = (char*)d_ws;
    float* sq  = (float*)ws;
    int*   idx = (int*)(ws + (size_t)NP * 4);
    float* x1  = (float*)(ws + (size_t)NP * 4 + (size_t)NP * KNN * 4);
    unsigned short* xhi = (unsigned short*)(ws + (size_t)NP * 4
                          + (size_t)NP * KNN * 4 + (size_t)NP * HDIM * 4);
    unsigned short* xlo = xhi + (size_t)NP * HDIM;
    unsigned short* wa0hi = xlo + (size_t)NP * HDIM;
    unsigned short* wa0lo = wa0hi + HDIM * 64;
    unsigned short* wa1hi = wa0lo + HDIM * 64;
    unsigned short* wa1lo = wa1hi + HDIM * 128;

    wsplit_kernel<<<(HDIM * 64 + 255) / 256, 256, 0, stream>>>(w0, wa0hi, wa0lo, 64);
    wsplit_kernel<<<(HDIM * 128 + 255) / 256, 256, 0, stream>>>(w1, wa1hi, wa1lo, 128);

    // layer 0 (D = 64)
    split_kernel<<<NP * 64 / 4 / 256, 256, 0, stream>>>(x, xhi, xlo, NP * 64 / 4);
    sq_kernel<64><<<NP / 4, 256, 0, stream>>>(x, sq);
    topk_kernel<64><<<NP / 32, 512, 0, stream>>>(xhi, xlo, sq, idx);
    mlp_kernel<64, 0><<<NP / 2, 512, 0, stream>>>(x, xhi, xlo, wa0hi, wa0lo,
                                                  w0, w2_0, idx, x1);

    // layer 1 (D = 128, x1 = [x, o0])
    split_kernel<<<NP * 128 / 4 / 256, 256, 0, stream>>>(x1, xhi, xlo, NP * 128 / 4);
    sq_kernel<128><<<NP / 4, 256, 0, stream>>>(x1, sq);
    topk_kernel<128><<<NP / 32, 512, 0, stream>>>(xhi, xlo, sq, idx);
    mlp_kernel<128, 1><<<NP / 2, 512, 0, stream>>>(x1, xhi, xlo, wa1hi, wa1lo,
                                                   w1, w2_1, idx, out);
}

// Round 22
// 1807.567 us; speedup vs baseline: 1.2327x; 1.2327x over previous
//
#include <hip/hip_runtime.h>
#include <hip/hip_bf16.h>

#define NP   16384
#define KNN  32
#define HDIM 128
#define ODIM 64

typedef __attribute__((ext_vector_type(8))) short bf16x8;
typedef __attribute__((ext_vector_type(4))) float f32x4;

#define BAR_LGKM() do { \
    asm volatile("s_waitcnt lgkmcnt(0)" ::: "memory"); \
    __builtin_amdgcn_sched_barrier(0); \
    __builtin_amdgcn_s_barrier(); \
    __builtin_amdgcn_sched_barrier(0); } while (0)
#define BAR_ALL() do { \
    asm volatile("s_waitcnt vmcnt(0) lgkmcnt(0)" ::: "memory"); \
    __builtin_amdgcn_sched_barrier(0); \
    __builtin_amdgcn_s_barrier(); \
    __builtin_amdgcn_sched_barrier(0); } while (0)

// ---------------- split fp32 -> bf16 (hi, lo) planes ----------------
__global__ __launch_bounds__(256)
void split_kernel(const float* __restrict__ X, unsigned short* __restrict__ hi,
                  unsigned short* __restrict__ lo, int n4) {
    const int i = blockIdx.x * 256 + threadIdx.x;
    if (i >= n4) return;
    const float4 v = reinterpret_cast<const float4*>(X)[i];
    const float vv[4] = {v.x, v.y, v.z, v.w};
    ushort4 h, l;
    unsigned short* hp = &h.x;
    unsigned short* lp = &l.x;
    #pragma unroll
    for (int c = 0; c < 4; ++c) {
        __hip_bfloat16 hb = __float2bfloat16(vv[c]);           // RNE
        const float hf = __bfloat162float(hb);
        __hip_bfloat16 lb = __float2bfloat16(vv[c] - hf);
        hp[c] = *reinterpret_cast<unsigned short*>(&hb);
        lp[c] = *reinterpret_cast<unsigned short*>(&lb);
    }
    reinterpret_cast<ushort4*>(hi)[i] = h;
    reinterpret_cast<ushort4*>(lo)[i] = l;
}

__global__ __launch_bounds__(256)
void wsplit_kernel(const float* __restrict__ W, unsigned short* __restrict__ hi,
                   unsigned short* __restrict__ lo, int Dd) {
    const int i = blockIdx.x * 256 + threadIdx.x;
    if (i >= HDIM * Dd) return;
    const int hh = i / Dd, d = i % Dd;
    const float v = W[(size_t)hh * (2 * Dd) + d];
    __hip_bfloat16 hb = __float2bfloat16(v);
    const float hf = __bfloat162float(hb);
    __hip_bfloat16 lb = __float2bfloat16(v - hf);
    hi[i] = *reinterpret_cast<unsigned short*>(&hb);
    lo[i] = *reinterpret_cast<unsigned short*>(&lb);
}

// ---------------- squared norms ----------------
template<int D>
__global__ __launch_bounds__(256)
void sq_kernel(const float* __restrict__ X, float* __restrict__ sq) {
    const int lane = threadIdx.x & 63;
    const int row  = blockIdx.x * 4 + (threadIdx.x >> 6);
    float s = 0.f;
    #pragma unroll
    for (int d = lane; d < D; d += 64) {
        const float v = X[(size_t)row * D + d];
        s = fmaf(v, v, s);
    }
    #pragma unroll
    for (int off = 32; off; off >>= 1) s += __shfl_down(s, off);
    if (lane == 0) sq[row] = s;
}

// ---------------- top-32 neighbors: MFMA scores + sorted register top-k ----
// TI=32 (2 A-rowblocks resident; B-frag reads amortized 2x), JC=128, 8 waves.
// ONE accumulator per rowblock (3-deep MFMA chain per k-step; saves 32 VGPRs
// vs R21 -> no scratch spills at launch_bounds(512,4)).  Single xjB; 16-row
// score buffer reused across 2 phases; staging issued after phase-0 barrier.
template<int D>
__global__ __launch_bounds__(512, 4)
void topk_kernel(const unsigned short* __restrict__ Xhi,
                 const unsigned short* __restrict__ Xlo,
                 const float* __restrict__ sq, int* __restrict__ topIdx) {
    constexpr int TI = 32, JC = 128, SS = JC + 1;
    constexpr int NT = NP / JC;
    constexpr int KQ = D / 8;
    constexpr int KS = D / 32;
    constexpr int PLSLOT = JC * KQ;
    constexpr int CALLS = 2 * PLSLOT / 512;
    __shared__ __align__(16) unsigned short xjB[2 * PLSLOT * 8];  // hi | lo
    __shared__ float scoresR[16 * SS];   // one rowblock at a time, stride 129

    const int t = threadIdx.x;
    const int lane = t & 63;
    const int waveU = __builtin_amdgcn_readfirstlane(t >> 6);
    const int rowBase = blockIdx.x * TI;
    const int l15 = lane & 15, l4 = lane >> 4;
    const float INF = __builtin_inff();
    const int jcol = 16 * waveU + l15;

    bf16x8 Ahi[2][KS], Alo[2][KS];
    #pragma unroll
    for (int rb = 0; rb < 2; ++rb)
        #pragma unroll
        for (int s = 0; s < KS; ++s) {
            const size_t off = (size_t)(rowBase + rb * 16 + l15) * D + 32 * s + 8 * l4;
            Ahi[rb][s] = *reinterpret_cast<const bf16x8*>(Xhi + off);
            Alo[rb][s] = *reinterpret_cast<const bf16x8*>(Xlo + off);
        }

    float tv[4]; int tidx[4]; float minv[4];   // [phase*2 + r]
    #pragma unroll
    for (int r = 0; r < 4; ++r) { tv[r] = -INF; tidx[r] = 0x7fffffff; minv[r] = -INF; }

    auto stageTile = [&](int jb) {
        #pragma unroll
        for (int c = 0; c < CALLS; ++c) {
            const int slotBase = (waveU * CALLS + c) * 64;
            const int sl = slotBase + lane;
            const int pl = sl / PLSLOT;
            const int ps = sl % PLSLOT;
            const int j  = ps / KQ;
            const int kq = (ps % KQ) ^ (j & (KQ - 1));
            const unsigned short* src =
                (pl ? Xlo : Xhi) + (size_t)(jb + j) * D + 8 * kq;
            __builtin_amdgcn_global_load_lds(
                (const __attribute__((address_space(1))) void*)src,
                (__attribute__((address_space(3))) void*)&xjB[(size_t)slotBase * 8],
                16, 0, 0);
        }
    };

#define SCAN_PHASE(BASE, JB) do {                                              \
    _Pragma("unroll")                                                          \
    for (int h = 0; h < 2; ++h) {                                              \
        float sv[2];                                                           \
        unsigned long long m[2];                                               \
        _Pragma("unroll")                                                      \
        for (int r = 0; r < 2; ++r) {                                          \
            sv[r] = scoresR[(2 * waveU + r) * SS + h * 64 + lane]              \
                  - (h ? sub1 : sub0);                                         \
            m[r] = __ballot(sv[r] > minv[(BASE) + r]);                         \
        }                                                                      \
        while (m[0] | m[1]) {                                                  \
            _Pragma("unroll")                                                  \
            for (int r = 0; r < 2; ++r) {                                      \
                if (m[r]) {                                                    \
                    const int l = __builtin_ctzll(m[r]);                       \
                    m[r] &= m[r] - 1;                                          \
                    const float cv = __int_as_float(                           \
                        __builtin_amdgcn_readlane(__float_as_int(sv[r]), l));  \
                    const int cj = (JB) + h * 64 + l;                          \
                    const float upv = __shfl_up(tv[(BASE) + r], 1);            \
                    const int   upi = __shfl_up(tidx[(BASE) + r], 1);          \
                    const bool ge = (lane < KNN) && (tv[(BASE) + r] >= cv);    \
                    const int pp = __popcll(__ballot(ge));                     \
                    if (lane == pp) { tv[(BASE)+r] = cv;  tidx[(BASE)+r] = cj; } \
                    else if (lane > pp && lane < KNN)                          \
                                    { tv[(BASE)+r] = upv; tidx[(BASE)+r] = upi; } \
                }                                                              \
            }                                                                  \
        }                                                                      \
        minv[(BASE) + 0] = __shfl(tv[(BASE) + 0], KNN - 1);                    \
        minv[(BASE) + 1] = __shfl(tv[(BASE) + 1], KNN - 1);                    \
    } } while (0)

    stageTile(0);
    BAR_ALL();

    for (int it = 0; it < NT; ++it) {
        const int jb = it * JC;
        const float sub0 = 0.5f * sq[jb + lane];
        const float sub1 = 0.5f * sq[jb + 64 + lane];

        // MFMA: 16 cols x 32 rows; ONE accumulator per rowblock (reg budget)
        f32x4 C0 = {0,0,0,0}, C1 = {0,0,0,0};
        #pragma unroll
        for (int s = 0; s < KS; ++s) {
            const int kq = 4 * s + l4;
            const int slot = jcol * KQ + (kq ^ (jcol & (KQ - 1)));
            const bf16x8 Bh = *reinterpret_cast<const bf16x8*>(&xjB[(size_t)slot * 8]);
            const bf16x8 Bl = *reinterpret_cast<const bf16x8*>(&xjB[(size_t)(PLSLOT + slot) * 8]);
            C0 = __builtin_amdgcn_mfma_f32_16x16x32_bf16(Ahi[0][s], Bh, C0, 0, 0, 0);
            C0 = __builtin_amdgcn_mfma_f32_16x16x32_bf16(Ahi[0][s], Bl, C0, 0, 0, 0);
            C0 = __builtin_amdgcn_mfma_f32_16x16x32_bf16(Alo[0][s], Bh, C0, 0, 0, 0);
            C1 = __builtin_amdgcn_mfma_f32_16x16x32_bf16(Ahi[1][s], Bh, C1, 0, 0, 0);
            C1 = __builtin_amdgcn_mfma_f32_16x16x32_bf16(Ahi[1][s], Bl, C1, 0, 0, 0);
            C1 = __builtin_amdgcn_mfma_f32_16x16x32_bf16(Alo[1][s], Bh, C1, 0, 0, 0);
        }

        // phase 0: rowblock 0
        #pragma unroll
        for (int r = 0; r < 4; ++r)
            scoresR[(4 * l4 + r) * SS + jcol] = C0[r];
        BAR_LGKM();                       // xjB reads + RB0 scatter done
        if (it + 1 < NT) stageTile(jb + JC);
        SCAN_PHASE(0, jb);
        BAR_LGKM();                       // RB0 scan reads done

        // phase 1: rowblock 1
        #pragma unroll
        for (int r = 0; r < 4; ++r)
            scoresR[(4 * l4 + r) * SS + jcol] = C1[r];
        BAR_LGKM();                       // RB1 scatter visible
        SCAN_PHASE(2, jb);
        BAR_ALL();                        // staging landed + RB1 reads done
    }

    if (lane < KNN) {
        #pragma unroll
        for (int p = 0; p < 2; ++p)
            #pragma unroll
            for (int r = 0; r < 2; ++r)
                topIdx[(size_t)(rowBase + p * 16 + 2 * waveU + r) * KNN + lane]
                    = tidx[p * 2 + r];
    }
#undef SCAN_PHASE
}

// ---------------- gather + MLP (MFMA) + pool + out (unchanged from R19) ----
template<int D, int LAYER>
__global__ __launch_bounds__(512, 4)
void mlp_kernel(const float* __restrict__ X,
                const unsigned short* __restrict__ Xhi,
                const unsigned short* __restrict__ Xlo,
                const unsigned short* __restrict__ WAhi,
                const unsigned short* __restrict__ WAlo,
                const float* __restrict__ W, const float* __restrict__ W2,
                const int* __restrict__ topIdx, float* __restrict__ out) {
    constexpr int RPB = 2;
    constexpr int KS = D / 32;
    constexpr int W2C  = HDIM + D;
    constexpr int SPL2 = 4;
    constexpr int CL   = W2C / SPL2;
    __shared__ float AT[D * HDIM];
    __shared__ float xi[RPB][D];
    __shared__ float hself_s[RPB][HDIM];
    __shared__ float part[RPB][2][HDIM];
    __shared__ int   idx_s[RPB][KNN];

    const int t = threadIdx.x;
    const int lane = t & 63;
    const int waveU = __builtin_amdgcn_readfirstlane(t >> 6);
    const int rowBase = blockIdx.x * RPB;
    const int l15 = lane & 15, l4 = lane >> 4;

    if (t < RPB * D / 4) {
        const int i = t / (D / 4), dg = t % (D / 4);
        const float4 v = *reinterpret_cast<const float4*>(
            X + (size_t)(rowBase + i) * D + 4 * dg);
        xi[i][4 * dg + 0] = v.x; xi[i][4 * dg + 1] = v.y;
        xi[i][4 * dg + 2] = v.z; xi[i][4 * dg + 3] = v.w;
    }
    if (t < RPB * KNN)
        idx_s[t >> 5][t & 31] = topIdx[(size_t)(rowBase + (t >> 5)) * KNN + (t & 31)];
    bf16x8 Ahi[KS], Alo[KS];
    #pragma unroll
    for (int s = 0; s < KS; ++s) {
        const size_t off = (size_t)(waveU * 16 + l15) * D + 32 * s + 8 * l4;
        Ahi[s] = *reinterpret_cast<const bf16x8*>(WAhi + off);
        Alo[s] = *reinterpret_cast<const bf16x8*>(WAlo + off);
    }
    for (int e = t; e < HDIM * D / 4; e += 512) {
        const int hh = e % HDIM, dg = e / HDIM;
        const float4 v = *reinterpret_cast<const float4*>(
            W + (size_t)hh * (2 * D) + D + 4 * dg);          // B = W[:, D:2D]
        AT[(4 * dg + 0) * HDIM + hh] = v.x; AT[(4 * dg + 1) * HDIM + hh] = v.y;
        AT[(4 * dg + 2) * HDIM + hh] = v.z; AT[(4 * dg + 3) * HDIM + hh] = v.w;
    }
    __syncthreads();

    if (t < RPB * HDIM) {
        const int row = t >> 7, hh = t & 127;
        float s = 0.f;
        #pragma unroll 8
        for (int d = 0; d < D; ++d)
            s = fmaf(AT[d * HDIM + hh], xi[row][d], s);
        hself_s[row][hh] = s;
    }
    __syncthreads();

    #pragma unroll
    for (int a = 0; a < 4; ++a) {
        const int row = a >> 1, kT = a & 1;
        const int nIdx = idx_s[row][kT * 16 + l15];
        bf16x8 Bh[KS], Bl[KS];
        #pragma unroll
        for (int s = 0; s < KS; ++s) {
            const size_t off = (size_t)nIdx * D + 32 * s + 8 * l4;
            Bh[s] = *reinterpret_cast<const bf16x8*>(Xhi + off);
            Bl[s] = *reinterpret_cast<const bf16x8*>(Xlo + off);
        }
        f32x4 Ca = {0,0,0,0}, Cb = {0,0,0,0}, Cc = {0,0,0,0};
        #pragma unroll
        for (int s = 0; s < KS; ++s) {
            Ca = __builtin_amdgcn_mfma_f32_16x16x32_bf16(Ahi[s], Bh[s], Ca, 0, 0, 0);
            Cb = __builtin_amdgcn_mfma_f32_16x16x32_bf16(Ahi[s], Bl[s], Cb, 0, 0, 0);
            Cc = __builtin_amdgcn_mfma_f32_16x16x32_bf16(Alo[s], Bh[s], Cc, 0, 0, 0);
        }
        float ps[4];
        #pragma unroll
        for (int r = 0; r < 4; ++r) {
            const float h = (Ca[r] + Cb[r]) + Cc[r]
                          + hself_s[row][waveU * 16 + 4 * l4 + r];
            ps[r] = fminf(1.f, fmaxf(-1.f, h));
        }
        #pragma unroll
        for (int off = 1; off <= 8; off <<= 1)
            #pragma unroll
            for (int r = 0; r < 4; ++r)
                ps[r] += __shfl_xor(ps[r], off);
        if (l15 == 0)
            #pragma unroll
            for (int r = 0; r < 4; ++r)
                part[row][kT][waveU * 16 + 4 * l4 + r] = ps[r] * (1.f / KNN);
    }
    __syncthreads();

    {
        const int og   = t / SPL2;
        const int spl  = t % SPL2;
        const int orow = og >> 6, o = og & 63;
        const int c0   = spl * CL;
        float s = 0.f;
        for (int c4 = 0; c4 < CL / 4; ++c4) {
            const int c = c0 + 4 * c4;
            const float4 w = *reinterpret_cast<const float4*>(W2 + (size_t)o * W2C + c);
            float vs[4];
            if (c < HDIM) {
                const float4 q0 = *reinterpret_cast<const float4*>(&part[orow][0][c]);
                const float4 q1 = *reinterpret_cast<const float4*>(&part[orow][1][c]);
                vs[0] = q0.x + q1.x; vs[1] = q0.y + q1.y;
                vs[2] = q0.z + q1.z; vs[3] = q0.w + q1.w;
            } else {
                const float4 xv = *reinterpret_cast<const float4*>(&xi[orow][c - HDIM]);
                vs[0] = xv.x; vs[1] = xv.y; vs[2] = xv.z; vs[3] = xv.w;
            }
            const float wv[4] = {w.x, w.y, w.z, w.w};
            #pragma unroll
            for (int j = 0; j < 4; ++j)
                s = fmaf(vs[j], wv[j], s);
        }
        #pragma unroll
        for (int off = SPL2 / 2; off; off >>= 1) s += __shfl_down(s, off);
        if (spl == 0) {
            if (LAYER == 0)
                out[(size_t)(rowBase + orow) * 128 + 64 + o] = s;
            else
                out[(size_t)(rowBase + orow) * ODIM + o] = s;
        }
    }
    if (LAYER == 0 && t < RPB * 64) {
        const int orow = t >> 6, d = t & 63;
        out[(size_t)(rowBase + orow) * 128 + d] = xi[orow][d];
    }
}

extern "C" void kernel_launch(void* const* d_in, const int* in_sizes, int n_in,
                              void* d_out, int out_size, void* d_ws, size_t ws_size,
                              hipStream_t stream) {
    const float* x    = (const float*)d_in[0];
    const float* w0   = (const float*)d_in[1];
    const float* w2_0 = (const float*)d_in[2];
    const float* w1   = (const float*)d_in[3];
    const float* w2_1 = (const float*)d_in[4];
    float* out = (float*)d_out;

    char* ws = (char*)d_ws;
    float* sq  = (float*)ws;
    int*   idx = (int*)(ws + (size_t)NP * 4);
    float* x1  = (float*)(ws + (size_t)NP * 4 + (size_t)NP * KNN * 4);
    unsigned short* xhi = (unsigned short*)(ws + (size_t)NP * 4
                          + (size_t)NP * KNN * 4 + (size_t)NP * HDIM * 4);
    unsigned short* xlo = xhi + (size_t)NP * HDIM;
    unsigned short* wa0hi = xlo + (size_t)NP * HDIM;
    unsigned short* wa0lo = wa0hi + HDIM * 64;
    unsigned short* wa1hi = wa0lo + HDIM * 64;
    unsigned short* wa1lo = wa1hi + HDIM * 128;

    wsplit_kernel<<<(HDIM * 64 + 255) / 256, 256, 0, stream>>>(w0, wa0hi, wa0lo, 64);
    wsplit_kernel<<<(HDIM * 128 + 255) / 256, 256, 0, stream>>>(w1, wa1hi, wa1lo, 128);

    // layer 0 (D = 64)
    split_kernel<<<NP * 64 / 4 / 256, 256, 0, stream>>>(x, xhi, xlo, NP * 64 / 4);
    sq_kernel<64><<<NP / 4, 256, 0, stream>>>(x, sq);
    topk_kernel<64><<<NP / 32, 512, 0, stream>>>(xhi, xlo, sq, idx);
    mlp_kernel<64, 0><<<NP / 2, 512, 0, stream>>>(x, xhi, xlo, wa0hi, wa0lo,
                                                  w0, w2_0, idx, x1);

    // layer 1 (D = 128, x1 = [x, o0])
    split_kernel<<<NP * 128 / 4 / 256, 256, 0, stream>>>(x1, xhi, xlo, NP * 128 / 4);
    sq_kernel<128><<<NP / 4, 256, 0, stream>>>(x1, sq);
    topk_kernel<128><<<NP / 32, 512, 0, stream>>>(xhi, xlo, sq, idx);
    mlp_kernel<128, 1><<<NP / 2, 512, 0, stream>>>(x1, xhi, xlo, wa1hi, wa1lo,
                                                   w1, w2_1, idx, out);
}

// Round 23
// 1766.387 us; speedup vs baseline: 1.2614x; 1.0233x over previous
//
#include <hip/hip_runtime.h>
#include <hip/hip_bf16.h>

#define NP   16384
#define KNN  32
#define HDIM 128
#define ODIM 64

typedef __attribute__((ext_vector_type(8))) short bf16x8;
typedef __attribute__((ext_vector_type(4))) float f32x4;

#define BAR_LGKM() do { \
    asm volatile("s_waitcnt lgkmcnt(0)" ::: "memory"); \
    __builtin_amdgcn_sched_barrier(0); \
    __builtin_amdgcn_s_barrier(); \
    __builtin_amdgcn_sched_barrier(0); } while (0)
#define BAR_ALL() do { \
    asm volatile("s_waitcnt vmcnt(0) lgkmcnt(0)" ::: "memory"); \
    __builtin_amdgcn_sched_barrier(0); \
    __builtin_amdgcn_s_barrier(); \
    __builtin_amdgcn_sched_barrier(0); } while (0)

// ---------------- fused: split fp32 -> bf16 hi/lo planes + squared norms ----
// one wave per row; lane loads D/64 floats (contiguous), converts, and the
// wave shfl-reduces the squared norm.
template<int D>
__global__ __launch_bounds__(256)
void splitsq_kernel(const float* __restrict__ X, unsigned short* __restrict__ hi,
                    unsigned short* __restrict__ lo, float* __restrict__ sq) {
    constexpr int EPL = D / 64;              // elems per lane (1 or 2)
    const int lane = threadIdx.x & 63;
    const int row  = blockIdx.x * 4 + (threadIdx.x >> 6);
    float s = 0.f;
    #pragma unroll
    for (int e = 0; e < EPL; ++e) {
        const int d = lane * EPL + e;        // contiguous per-lane chunk
        const float v = X[(size_t)row * D + d];
        s = fmaf(v, v, s);
        __hip_bfloat16 hb = __float2bfloat16(v);            // RNE
        const float hf = __bfloat162float(hb);
        __hip_bfloat16 lb = __float2bfloat16(v - hf);
        hi[(size_t)row * D + d] = *reinterpret_cast<unsigned short*>(&hb);
        lo[(size_t)row * D + d] = *reinterpret_cast<unsigned short*>(&lb);
    }
    #pragma unroll
    for (int off = 32; off; off >>= 1) s += __shfl_down(s, off);
    if (lane == 0) sq[row] = s;
}

__global__ __launch_bounds__(256)
void wsplit_kernel(const float* __restrict__ W, unsigned short* __restrict__ hi,
                   unsigned short* __restrict__ lo, int Dd) {
    const int i = blockIdx.x * 256 + threadIdx.x;
    if (i >= HDIM * Dd) return;
    const int hh = i / Dd, d = i % Dd;
    const float v = W[(size_t)hh * (2 * Dd) + d];
    __hip_bfloat16 hb = __float2bfloat16(v);
    const float hf = __bfloat162float(hb);
    __hip_bfloat16 lb = __float2bfloat16(v - hf);
    hi[i] = *reinterpret_cast<unsigned short*>(&hb);
    lo[i] = *reinterpret_cast<unsigned short*>(&lb);
}

// ---------------- top-32 neighbors: MFMA scores + sorted register top-k ----
// TI=32 (2 A-rowblocks resident; B-frag reads amortized 2x), JC=128, 8 waves.
// One accumulator per rowblock (no spills at launch_bounds(512,4)).
// D=64: TWO score buffers -> both rowblocks scatter before ONE barrier,
// both scans run back-to-back, ONE end barrier (2 barriers/tile, LDS 49.3KB).
// D=128: single score buffer, 4 barriers/tile (LDS 74.2KB), as R22.
template<int D>
__global__ __launch_bounds__(512, 4)
void topk_kernel(const unsigned short* __restrict__ Xhi,
                 const unsigned short* __restrict__ Xlo,
                 const float* __restrict__ sq, int* __restrict__ topIdx) {
    constexpr int TI = 32, JC = 128, SS = JC + 1;
    constexpr int NT = NP / JC;
    constexpr int KQ = D / 8;
    constexpr int KS = D / 32;
    constexpr int PLSLOT = JC * KQ;
    constexpr int CALLS = 2 * PLSLOT / 512;
    constexpr int NSB = (D == 64) ? 2 : 1;   // score buffers
    __shared__ __align__(16) unsigned short xjB[2 * PLSLOT * 8];  // hi | lo
    __shared__ float scoresR[NSB][16 * SS];  // [buf][row][col], stride 129

    const int t = threadIdx.x;
    const int lane = t & 63;
    const int waveU = __builtin_amdgcn_readfirstlane(t >> 6);
    const int rowBase = blockIdx.x * TI;
    const int l15 = lane & 15, l4 = lane >> 4;
    const float INF = __builtin_inff();
    const int jcol = 16 * waveU + l15;

    bf16x8 Ahi[2][KS], Alo[2][KS];
    #pragma unroll
    for (int rb = 0; rb < 2; ++rb)
        #pragma unroll
        for (int s = 0; s < KS; ++s) {
            const size_t off = (size_t)(rowBase + rb * 16 + l15) * D + 32 * s + 8 * l4;
            Ahi[rb][s] = *reinterpret_cast<const bf16x8*>(Xhi + off);
            Alo[rb][s] = *reinterpret_cast<const bf16x8*>(Xlo + off);
        }

    float tv[4]; int tidx[4]; float minv[4];   // [rowblock*2 + r]
    #pragma unroll
    for (int r = 0; r < 4; ++r) { tv[r] = -INF; tidx[r] = 0x7fffffff; minv[r] = -INF; }

    auto stageTile = [&](int jb) {
        #pragma unroll
        for (int c = 0; c < CALLS; ++c) {
            const int slotBase = (waveU * CALLS + c) * 64;
            const int sl = slotBase + lane;
            const int pl = sl / PLSLOT;
            const int ps = sl % PLSLOT;
            const int j  = ps / KQ;
            const int kq = (ps % KQ) ^ (j & (KQ - 1));
            const unsigned short* src =
                (pl ? Xlo : Xhi) + (size_t)(jb + j) * D + 8 * kq;
            __builtin_amdgcn_global_load_lds(
                (const __attribute__((address_space(1))) void*)src,
                (__attribute__((address_space(3))) void*)&xjB[(size_t)slotBase * 8],
                16, 0, 0);
        }
    };

#define SCAN_PHASE(BASE, BUF, JB) do {                                         \
    _Pragma("unroll")                                                          \
    for (int h = 0; h < 2; ++h) {                                              \
        float sv[2];                                                           \
        unsigned long long m[2];                                               \
        _Pragma("unroll")                                                      \
        for (int r = 0; r < 2; ++r) {                                          \
            sv[r] = scoresR[BUF][(2 * waveU + r) * SS + h * 64 + lane]         \
                  - (h ? sub1 : sub0);                                         \
            m[r] = __ballot(sv[r] > minv[(BASE) + r]);                         \
        }                                                                      \
        while (m[0] | m[1]) {                                                  \
            _Pragma("unroll")                                                  \
            for (int r = 0; r < 2; ++r) {                                      \
                if (m[r]) {                                                    \
                    const int l = __builtin_ctzll(m[r]);                       \
                    m[r] &= m[r] - 1;                                          \
                    const float cv = __int_as_float(                           \
                        __builtin_amdgcn_readlane(__float_as_int(sv[r]), l));  \
                    const int cj = (JB) + h * 64 + l;                          \
                    const float upv = __shfl_up(tv[(BASE) + r], 1);            \
                    const int   upi = __shfl_up(tidx[(BASE) + r], 1);          \
                    const bool ge = (lane < KNN) && (tv[(BASE) + r] >= cv);    \
                    const int pp = __popcll(__ballot(ge));                     \
                    if (lane == pp) { tv[(BASE)+r] = cv;  tidx[(BASE)+r] = cj; } \
                    else if (lane > pp && lane < KNN)                          \
                                    { tv[(BASE)+r] = upv; tidx[(BASE)+r] = upi; } \
                }                                                              \
            }                                                                  \
        }                                                                      \
        minv[(BASE) + 0] = __shfl(tv[(BASE) + 0], KNN - 1);                    \
        minv[(BASE) + 1] = __shfl(tv[(BASE) + 1], KNN - 1);                    \
    } } while (0)

    stageTile(0);
    BAR_ALL();

    for (int it = 0; it < NT; ++it) {
        const int jb = it * JC;
        const float sub0 = 0.5f * sq[jb + lane];
        const float sub1 = 0.5f * sq[jb + 64 + lane];

        // MFMA: 16 cols x 32 rows; one accumulator per rowblock
        f32x4 C0 = {0,0,0,0}, C1 = {0,0,0,0};
        #pragma unroll
        for (int s = 0; s < KS; ++s) {
            const int kq = 4 * s + l4;
            const int slot = jcol * KQ + (kq ^ (jcol & (KQ - 1)));
            const bf16x8 Bh = *reinterpret_cast<const bf16x8*>(&xjB[(size_t)slot * 8]);
            const bf16x8 Bl = *reinterpret_cast<const bf16x8*>(&xjB[(size_t)(PLSLOT + slot) * 8]);
            C0 = __builtin_amdgcn_mfma_f32_16x16x32_bf16(Ahi[0][s], Bh, C0, 0, 0, 0);
            C0 = __builtin_amdgcn_mfma_f32_16x16x32_bf16(Ahi[0][s], Bl, C0, 0, 0, 0);
            C0 = __builtin_amdgcn_mfma_f32_16x16x32_bf16(Alo[0][s], Bh, C0, 0, 0, 0);
            C1 = __builtin_amdgcn_mfma_f32_16x16x32_bf16(Ahi[1][s], Bh, C1, 0, 0, 0);
            C1 = __builtin_amdgcn_mfma_f32_16x16x32_bf16(Ahi[1][s], Bl, C1, 0, 0, 0);
            C1 = __builtin_amdgcn_mfma_f32_16x16x32_bf16(Alo[1][s], Bh, C1, 0, 0, 0);
        }

        if (NSB == 2) {
            // D=64: both rowblocks scatter to separate buffers, 2 barriers/tile
            #pragma unroll
            for (int r = 0; r < 4; ++r) {
                scoresR[0][(4 * l4 + r) * SS + jcol] = C0[r];
                scoresR[1][(4 * l4 + r) * SS + jcol] = C1[r];
            }
            BAR_LGKM();                   // xjB reads + both scatters done
            if (it + 1 < NT) stageTile(jb + JC);
            SCAN_PHASE(0, 0, jb);
            SCAN_PHASE(2, 1, jb);
            BAR_ALL();                    // staging landed + scan reads done
        } else {
            // D=128: single buffer, two phases, 4 barriers/tile
            #pragma unroll
            for (int r = 0; r < 4; ++r)
                scoresR[0][(4 * l4 + r) * SS + jcol] = C0[r];
            BAR_LGKM();
            if (it + 1 < NT) stageTile(jb + JC);
            SCAN_PHASE(0, 0, jb);
            BAR_LGKM();
            #pragma unroll
            for (int r = 0; r < 4; ++r)
                scoresR[0][(4 * l4 + r) * SS + jcol] = C1[r];
            BAR_LGKM();
            SCAN_PHASE(2, 0, jb);
            BAR_ALL();
        }
    }

    if (lane < KNN) {
        #pragma unroll
        for (int p = 0; p < 2; ++p)
            #pragma unroll
            for (int r = 0; r < 2; ++r)
                topIdx[(size_t)(rowBase + p * 16 + 2 * waveU + r) * KNN + lane]
                    = tidx[p * 2 + r];
    }
#undef SCAN_PHASE
}

// ---------------- gather + MLP (MFMA) + pool + out (unchanged from R19) ----
template<int D, int LAYER>
__global__ __launch_bounds__(512, 4)
void mlp_kernel(const float* __restrict__ X,
                const unsigned short* __restrict__ Xhi,
                const unsigned short* __restrict__ Xlo,
                const unsigned short* __restrict__ WAhi,
                const unsigned short* __restrict__ WAlo,
                const float* __restrict__ W, const float* __restrict__ W2,
                const int* __restrict__ topIdx, float* __restrict__ out) {
    constexpr int RPB = 2;
    constexpr int KS = D / 32;
    constexpr int W2C  = HDIM + D;
    constexpr int SPL2 = 4;
    constexpr int CL   = W2C / SPL2;
    __shared__ float AT[D * HDIM];
    __shared__ float xi[RPB][D];
    __shared__ float hself_s[RPB][HDIM];
    __shared__ float part[RPB][2][HDIM];
    __shared__ int   idx_s[RPB][KNN];

    const int t = threadIdx.x;
    const int lane = t & 63;
    const int waveU = __builtin_amdgcn_readfirstlane(t >> 6);
    const int rowBase = blockIdx.x * RPB;
    const int l15 = lane & 15, l4 = lane >> 4;

    if (t < RPB * D / 4) {
        const int i = t / (D / 4), dg = t % (D / 4);
        const float4 v = *reinterpret_cast<const float4*>(
            X + (size_t)(rowBase + i) * D + 4 * dg);
        xi[i][4 * dg + 0] = v.x; xi[i][4 * dg + 1] = v.y;
        xi[i][4 * dg + 2] = v.z; xi[i][4 * dg + 3] = v.w;
    }
    if (t < RPB * KNN)
        idx_s[t >> 5][t & 31] = topIdx[(size_t)(rowBase + (t >> 5)) * KNN + (t & 31)];
    bf16x8 Ahi[KS], Alo[KS];
    #pragma unroll
    for (int s = 0; s < KS; ++s) {
        const size_t off = (size_t)(waveU * 16 + l15) * D + 32 * s + 8 * l4;
        Ahi[s] = *reinterpret_cast<const bf16x8*>(WAhi + off);
        Alo[s] = *reinterpret_cast<const bf16x8*>(WAlo + off);
    }
    for (int e = t; e < HDIM * D / 4; e += 512) {
        const int hh = e % HDIM, dg = e / HDIM;
        const float4 v = *reinterpret_cast<const float4*>(
            W + (size_t)hh * (2 * D) + D + 4 * dg);          // B = W[:, D:2D]
        AT[(4 * dg + 0) * HDIM + hh] = v.x; AT[(4 * dg + 1) * HDIM + hh] = v.y;
        AT[(4 * dg + 2) * HDIM + hh] = v.z; AT[(4 * dg + 3) * HDIM + hh] = v.w;
    }
    __syncthreads();

    if (t < RPB * HDIM) {
        const int row = t >> 7, hh = t & 127;
        float s = 0.f;
        #pragma unroll 8
        for (int d = 0; d < D; ++d)
            s = fmaf(AT[d * HDIM + hh], xi[row][d], s);
        hself_s[row][hh] = s;
    }
    __syncthreads();

    #pragma unroll
    for (int a = 0; a < 4; ++a) {
        const int row = a >> 1, kT = a & 1;
        const int nIdx = idx_s[row][kT * 16 + l15];
        bf16x8 Bh[KS], Bl[KS];
        #pragma unroll
        for (int s = 0; s < KS; ++s) {
            const size_t off = (size_t)nIdx * D + 32 * s + 8 * l4;
            Bh[s] = *reinterpret_cast<const bf16x8*>(Xhi + off);
            Bl[s] = *reinterpret_cast<const bf16x8*>(Xlo + off);
        }
        f32x4 Ca = {0,0,0,0}, Cb = {0,0,0,0}, Cc = {0,0,0,0};
        #pragma unroll
        for (int s = 0; s < KS; ++s) {
            Ca = __builtin_amdgcn_mfma_f32_16x16x32_bf16(Ahi[s], Bh[s], Ca, 0, 0, 0);
            Cb = __builtin_amdgcn_mfma_f32_16x16x32_bf16(Ahi[s], Bl[s], Cb, 0, 0, 0);
            Cc = __builtin_amdgcn_mfma_f32_16x16x32_bf16(Alo[s], Bh[s], Cc, 0, 0, 0);
        }
        float ps[4];
        #pragma unroll
        for (int r = 0; r < 4; ++r) {
            const float h = (Ca[r] + Cb[r]) + Cc[r]
                          + hself_s[row][waveU * 16 + 4 * l4 + r];
            ps[r] = fminf(1.f, fmaxf(-1.f, h));
        }
        #pragma unroll
        for (int off = 1; off <= 8; off <<= 1)
            #pragma unroll
            for (int r = 0; r < 4; ++r)
                ps[r] += __shfl_xor(ps[r], off);
        if (l15 == 0)
            #pragma unroll
            for (int r = 0; r < 4; ++r)
                part[row][kT][waveU * 16 + 4 * l4 + r] = ps[r] * (1.f / KNN);
    }
    __syncthreads();

    {
        const int og   = t / SPL2;
        const int spl  = t % SPL2;
        const int orow = og >> 6, o = og & 63;
        const int c0   = spl * CL;
        float s = 0.f;
        for (int c4 = 0; c4 < CL / 4; ++c4) {
            const int c = c0 + 4 * c4;
            const float4 w = *reinterpret_cast<const float4*>(W2 + (size_t)o * W2C + c);
            float vs[4];
            if (c < HDIM) {
                const float4 q0 = *reinterpret_cast<const float4*>(&part[orow][0][c]);
                const float4 q1 = *reinterpret_cast<const float4*>(&part[orow][1][c]);
                vs[0] = q0.x + q1.x; vs[1] = q0.y + q1.y;
                vs[2] = q0.z + q1.z; vs[3] = q0.w + q1.w;
            } else {
                const float4 xv = *reinterpret_cast<const float4*>(&xi[orow][c - HDIM]);
                vs[0] = xv.x; vs[1] = xv.y; vs[2] = xv.z; vs[3] = xv.w;
            }
            const float wv[4] = {w.x, w.y, w.z, w.w};
            #pragma unroll
            for (int j = 0; j < 4; ++j)
                s = fmaf(vs[j], wv[j], s);
        }
        #pragma unroll
        for (int off = SPL2 / 2; off; off >>= 1) s += __shfl_down(s, off);
        if (spl == 0) {
            if (LAYER == 0)
                out[(size_t)(rowBase + orow) * 128 + 64 + o] = s;
            else
                out[(size_t)(rowBase + orow) * ODIM + o] = s;
        }
    }
    if (LAYER == 0 && t < RPB * 64) {
        const int orow = t >> 6, d = t & 63;
        out[(size_t)(rowBase + orow) * 128 + d] = xi[orow][d];
    }
}

extern "C" void kernel_launch(void* const* d_in, const int* in_sizes, int n_in,
                              void* d_out, int out_size, void* d_ws, size_t ws_size,
                              hipStream_t stream) {
    const float* x    = (const float*)d_in[0];
    const float* w0   = (const float*)d_in[1];
    const float* w2_0 = (const float*)d_in[2];
    const float* w1   = (const float*)d_in[3];
    const float* w2_1 = (const float*)d_in[4];
    float* out = (float*)d_out;

    char* ws = (char*)d_ws;
    float* sq  = (float*)ws;
    int*   idx = (int*)(ws + (size_t)NP * 4);
    float* x1  = (float*)(ws + (size_t)NP * 4 + (size_t)NP * KNN * 4);
    unsigned short* xhi = (unsigned short*)(ws + (size_t)NP * 4
                          + (size_t)NP * KNN * 4 + (size_t)NP * HDIM * 4);
    unsigned short* xlo = xhi + (size_t)NP * HDIM;
    unsigned short* wa0hi = xlo + (size_t)NP * HDIM;
    unsigned short* wa0lo = wa0hi + HDIM * 64;
    unsigned short* wa1hi = wa0lo + HDIM * 64;
    unsigned short* wa1lo = wa1hi + HDIM * 128;

    wsplit_kernel<<<(HDIM * 64 + 255) / 256, 256, 0, stream>>>(w0, wa0hi, wa0lo, 64);
    wsplit_kernel<<<(HDIM * 128 + 255) / 256, 256, 0, stream>>>(w1, wa1hi, wa1lo, 128);

    // layer 0 (D = 64)
    splitsq_kernel<64><<<NP / 4, 256, 0, stream>>>(x, xhi, xlo, sq);
    topk_kernel<64><<<NP / 32, 512, 0, stream>>>(xhi, xlo, sq, idx);
    mlp_kernel<64, 0><<<NP / 2, 512, 0, stream>>>(x, xhi, xlo, wa0hi, wa0lo,
                                                  w0, w2_0, idx, x1);

    // layer 1 (D = 128, x1 = [x, o0])
    splitsq_kernel<128><<<NP / 4, 256, 0, stream>>>(x1, xhi, xlo, sq);
    topk_kernel<128><<<NP / 32, 512, 0, stream>>>(xhi, xlo, sq, idx);
    mlp_kernel<128, 1><<<NP / 2, 512, 0, stream>>>(x1, xhi, xlo, wa1hi, wa1lo,
                                                   w1, w2_1, idx, out);
}

// Round 25
// 1763.041 us; speedup vs baseline: 1.2638x; 1.0019x over previous
//
#include <hip/hip_runtime.h>
#include <hip/hip_bf16.h>

#define NP   16384
#define KNN  32
#define HDIM 128
#define ODIM 64

typedef __attribute__((ext_vector_type(8))) short bf16x8;
typedef __attribute__((ext_vector_type(4))) float f32x4;

#define BAR_LGKM() do { \
    asm volatile("s_waitcnt lgkmcnt(0)" ::: "memory"); \
    __builtin_amdgcn_sched_barrier(0); \
    __builtin_amdgcn_s_barrier(); \
    __builtin_amdgcn_sched_barrier(0); } while (0)
#define BAR_ALL() do { \
    asm volatile("s_waitcnt vmcnt(0) lgkmcnt(0)" ::: "memory"); \
    __builtin_amdgcn_sched_barrier(0); \
    __builtin_amdgcn_s_barrier(); \
    __builtin_amdgcn_sched_barrier(0); } while (0)

// ---------------- fused: split fp32 -> bf16 hi/lo planes + squared norms ----
template<int D>
__global__ __launch_bounds__(256)
void splitsq_kernel(const float* __restrict__ X, unsigned short* __restrict__ hi,
                    unsigned short* __restrict__ lo, float* __restrict__ sq) {
    constexpr int EPL = D / 64;
    const int lane = threadIdx.x & 63;
    const int row  = blockIdx.x * 4 + (threadIdx.x >> 6);
    float s = 0.f;
    #pragma unroll
    for (int e = 0; e < EPL; ++e) {
        const int d = lane * EPL + e;
        const float v = X[(size_t)row * D + d];
        s = fmaf(v, v, s);
        __hip_bfloat16 hb = __float2bfloat16(v);            // RNE
        const float hf = __bfloat162float(hb);
        __hip_bfloat16 lb = __float2bfloat16(v - hf);
        hi[(size_t)row * D + d] = *reinterpret_cast<unsigned short*>(&hb);
        lo[(size_t)row * D + d] = *reinterpret_cast<unsigned short*>(&lb);
    }
    #pragma unroll
    for (int off = 32; off; off >>= 1) s += __shfl_down(s, off);
    if (lane == 0) sq[row] = s;
}

__global__ __launch_bounds__(256)
void wsplit_kernel(const float* __restrict__ W, unsigned short* __restrict__ hi,
                   unsigned short* __restrict__ lo, int Dd) {
    const int i = blockIdx.x * 256 + threadIdx.x;
    if (i >= HDIM * Dd) return;
    const int hh = i / Dd, d = i % Dd;
    const float v = W[(size_t)hh * (2 * Dd) + d];
    __hip_bfloat16 hb = __float2bfloat16(v);
    const float hf = __bfloat162float(hb);
    __hip_bfloat16 lb = __float2bfloat16(v - hf);
    hi[i] = *reinterpret_cast<unsigned short*>(&hb);
    lo[i] = *reinterpret_cast<unsigned short*>(&lb);
}

// ---------------- top-32 neighbors: MFMA scores + sorted register top-k ----
// TI=32 (2 A-rowblocks resident; B-frag reads amortized 2x), JC=128, 8 waves.
// One accumulator per rowblock (no spills at launch_bounds(512,4)).
// D=64: TWO score buffers -> both rowblocks scatter before ONE barrier,
// both scans run back-to-back, ONE end barrier (2 barriers/tile, LDS 49.3KB).
// D=128: single score buffer, 4 barriers/tile (LDS 74.2KB), as R22.
template<int D>
__global__ __launch_bounds__(512, 4)
void topk_kernel(const unsigned short* __restrict__ Xhi,
                 const unsigned short* __restrict__ Xlo,
                 const float* __restrict__ sq, int* __restrict__ topIdx) {
    constexpr int TI = 32, JC = 128, SS = JC + 1;
    constexpr int NT = NP / JC;
    constexpr int KQ = D / 8;
    constexpr int KS = D / 32;
    constexpr int PLSLOT = JC * KQ;
    constexpr int CALLS = 2 * PLSLOT / 512;
    constexpr int NSB = (D == 64) ? 2 : 1;   // score buffers
    __shared__ __align__(16) unsigned short xjB[2 * PLSLOT * 8];  // hi | lo
    __shared__ float scoresR[NSB][16 * SS];  // [buf][row][col], stride 129

    const int t = threadIdx.x;
    const int lane = t & 63;
    const int waveU = __builtin_amdgcn_readfirstlane(t >> 6);
    const int rowBase = blockIdx.x * TI;
    const int l15 = lane & 15, l4 = lane >> 4;
    const float INF = __builtin_inff();
    const int jcol = 16 * waveU + l15;

    bf16x8 Ahi[2][KS], Alo[2][KS];
    #pragma unroll
    for (int rb = 0; rb < 2; ++rb)
        #pragma unroll
        for (int s = 0; s < KS; ++s) {
            const size_t off = (size_t)(rowBase + rb * 16 + l15) * D + 32 * s + 8 * l4;
            Ahi[rb][s] = *reinterpret_cast<const bf16x8*>(Xhi + off);
            Alo[rb][s] = *reinterpret_cast<const bf16x8*>(Xlo + off);
        }

    float tv[4]; int tidx[4]; float minv[4];   // [rowblock*2 + r]
    #pragma unroll
    for (int r = 0; r < 4; ++r) { tv[r] = -INF; tidx[r] = 0x7fffffff; minv[r] = -INF; }

    auto stageTile = [&](int jb) {
        #pragma unroll
        for (int c = 0; c < CALLS; ++c) {
            const int slotBase = (waveU * CALLS + c) * 64;
            const int sl = slotBase + lane;
            const int pl = sl / PLSLOT;
            const int ps = sl % PLSLOT;
            const int j  = ps / KQ;
            const int kq = (ps % KQ) ^ (j & (KQ - 1));
            const unsigned short* src =
                (pl ? Xlo : Xhi) + (size_t)(jb + j) * D + 8 * kq;
            __builtin_amdgcn_global_load_lds(
                (const __attribute__((address_space(1))) void*)src,
                (__attribute__((address_space(3))) void*)&xjB[(size_t)slotBase * 8],
                16, 0, 0);
        }
    };

#define SCAN_PHASE(BASE, BUF, JB) do {                                         \
    _Pragma("unroll")                                                          \
    for (int h = 0; h < 2; ++h) {                                              \
        float sv[2];                                                           \
        unsigned long long m[2];                                               \
        _Pragma("unroll")                                                      \
        for (int r = 0; r < 2; ++r) {                                          \
            sv[r] = scoresR[BUF][(2 * waveU + r) * SS + h * 64 + lane]         \
                  - (h ? sub1 : sub0);                                         \
            m[r] = __ballot(sv[r] > minv[(BASE) + r]);                         \
        }                                                                      \
        while (m[0] | m[1]) {                                                  \
            _Pragma("unroll")                                                  \
            for (int r = 0; r < 2; ++r) {                                      \
                if (m[r]) {                                                    \
                    const int l = __builtin_ctzll(m[r]);                       \
                    m[r] &= m[r] - 1;                                          \
                    const float cv = __int_as_float(                           \
                        __builtin_amdgcn_readlane(__float_as_int(sv[r]), l));  \
                    const int cj = (JB) + h * 64 + l;                          \
                    const float upv = __shfl_up(tv[(BASE) + r], 1);            \
                    const int   upi = __shfl_up(tidx[(BASE) + r], 1);          \
                    const bool ge = (lane < KNN) && (tv[(BASE) + r] >= cv);    \
                    const int pp = __popcll(__ballot(ge));                     \
                    if (lane == pp) { tv[(BASE)+r] = cv;  tidx[(BASE)+r] = cj; } \
                    else if (lane > pp && lane < KNN)                          \
                                    { tv[(BASE)+r] = upv; tidx[(BASE)+r] = upi; } \
                }                                                              \
            }                                                                  \
        }                                                                      \
        minv[(BASE) + 0] = __shfl(tv[(BASE) + 0], KNN - 1);                    \
        minv[(BASE) + 1] = __shfl(tv[(BASE) + 1], KNN - 1);                    \
    } } while (0)

    stageTile(0);
    BAR_ALL();

    for (int it = 0; it < NT; ++it) {
        const int jb = it * JC;
        const float sub0 = 0.5f * sq[jb + lane];
        const float sub1 = 0.5f * sq[jb + 64 + lane];

        // MFMA: 16 cols x 32 rows; one accumulator per rowblock
        f32x4 C0 = {0,0,0,0}, C1 = {0,0,0,0};
        #pragma unroll
        for (int s = 0; s < KS; ++s) {
            const int kq = 4 * s + l4;
            const int slot = jcol * KQ + (kq ^ (jcol & (KQ - 1)));
            const bf16x8 Bh = *reinterpret_cast<const bf16x8*>(&xjB[(size_t)slot * 8]);
            const bf16x8 Bl = *reinterpret_cast<const bf16x8*>(&xjB[(size_t)(PLSLOT + slot) * 8]);
            C0 = __builtin_amdgcn_mfma_f32_16x16x32_bf16(Ahi[0][s], Bh, C0, 0, 0, 0);
            C0 = __builtin_amdgcn_mfma_f32_16x16x32_bf16(Ahi[0][s], Bl, C0, 0, 0, 0);
            C0 = __builtin_amdgcn_mfma_f32_16x16x32_bf16(Alo[0][s], Bh, C0, 0, 0, 0);
            C1 = __builtin_amdgcn_mfma_f32_16x16x32_bf16(Ahi[1][s], Bh, C1, 0, 0, 0);
            C1 = __builtin_amdgcn_mfma_f32_16x16x32_bf16(Ahi[1][s], Bl, C1, 0, 0, 0);
            C1 = __builtin_amdgcn_mfma_f32_16x16x32_bf16(Alo[1][s], Bh, C1, 0, 0, 0);
        }

        if (NSB == 2) {
            // D=64: both rowblocks scatter to separate buffers, 2 barriers/tile
            #pragma unroll
            for (int r = 0; r < 4; ++r) {
                scoresR[0][(4 * l4 + r) * SS + jcol] = C0[r];
                scoresR[1][(4 * l4 + r) * SS + jcol] = C1[r];
            }
            BAR_LGKM();                   // xjB reads + both scatters done
            if (it + 1 < NT) stageTile(jb + JC);
            SCAN_PHASE(0, 0, jb);
            SCAN_PHASE(2, 1, jb);
            BAR_ALL();                    // staging landed + scan reads done
        } else {
            // D=128: single buffer, two phases, 4 barriers/tile
            #pragma unroll
            for (int r = 0; r < 4; ++r)
                scoresR[0][(4 * l4 + r) * SS + jcol] = C0[r];
            BAR_LGKM();
            if (it + 1 < NT) stageTile(jb + JC);
            SCAN_PHASE(0, 0, jb);
            BAR_LGKM();
            #pragma unroll
            for (int r = 0; r < 4; ++r)
                scoresR[0][(4 * l4 + r) * SS + jcol] = C1[r];
            BAR_LGKM();
            SCAN_PHASE(2, 0, jb);
            BAR_ALL();
        }
    }

    if (lane < KNN) {
        #pragma unroll
        for (int p = 0; p < 2; ++p)
            #pragma unroll
            for (int r = 0; r < 2; ++r)
                topIdx[(size_t)(rowBase + p * 16 + 2 * waveU + r) * KNN + lane]
                    = tidx[p * 2 + r];
    }
#undef SCAN_PHASE
}

// ---------------- gather + MLP (MFMA) + pool + out ----------
template<int D, int LAYER>
__global__ __launch_bounds__(512, 4)
void mlp_kernel(const float* __restrict__ X,
                const unsigned short* __restrict__ Xhi,
                const unsigned short* __restrict__ Xlo,
                const unsigned short* __restrict__ WAhi,
                const unsigned short* __restrict__ WAlo,
                const float* __restrict__ W, const float* __restrict__ W2,
                const int* __restrict__ topIdx, float* __restrict__ out) {
    constexpr int RPB = 2;
    constexpr int KS = D / 32;
    constexpr int W2C  = HDIM + D;
    constexpr int SPL2 = 4;
    constexpr int CL   = W2C / SPL2;
    __shared__ float AT[D * HDIM];
    __shared__ float xi[RPB][D];
    __shared__ float hself_s[RPB][HDIM];
    __shared__ float part[RPB][2][HDIM];
    __shared__ int   idx_s[RPB][KNN];

    const int t = threadIdx.x;
    const int lane = t & 63;
    const int waveU = __builtin_amdgcn_readfirstlane(t >> 6);
    const int rowBase = blockIdx.x * RPB;
    const int l15 = lane & 15, l4 = lane >> 4;

    if (t < RPB * D / 4) {
        const int i = t / (D / 4), dg = t % (D / 4);
        const float4 v = *reinterpret_cast<const float4*>(
            X + (size_t)(rowBase + i) * D + 4 * dg);
        xi[i][4 * dg + 0] = v.x; xi[i][4 * dg + 1] = v.y;
        xi[i][4 * dg + 2] = v.z; xi[i][4 * dg + 3] = v.w;
    }
    if (t < RPB * KNN)
        idx_s[t >> 5][t & 31] = topIdx[(size_t)(rowBase + (t >> 5)) * KNN + (t & 31)];
    bf16x8 Ahi[KS], Alo[KS];
    #pragma unroll
    for (int s = 0; s < KS; ++s) {
        const size_t off = (size_t)(waveU * 16 + l15) * D + 32 * s + 8 * l4;
        Ahi[s] = *reinterpret_cast<const bf16x8*>(WAhi + off);
        Alo[s] = *reinterpret_cast<const bf16x8*>(WAlo + off);
    }
    for (int e = t; e < HDIM * D / 4; e += 512) {
        const int hh = e % HDIM, dg = e / HDIM;
        const float4 v = *reinterpret_cast<const float4*>(
            W + (size_t)hh * (2 * D) + D + 4 * dg);          // B = W[:, D:2D]
        AT[(4 * dg + 0) * HDIM + hh] = v.x; AT[(4 * dg + 1) * HDIM + hh] = v.y;
        AT[(4 * dg + 2) * HDIM + hh] = v.z; AT[(4 * dg + 3) * HDIM + hh] = v.w;
    }
    __syncthreads();

    if (t < RPB * HDIM) {
        const int row = t >> 7, hh = t & 127;
        float s = 0.f;
        #pragma unroll 8
        for (int d = 0; d < D; ++d)
            s = fmaf(AT[d * HDIM + hh], xi[row][d], s);
        hself_s[row][hh] = s;
    }
    __syncthreads();

    #pragma unroll
    for (int a = 0; a < 4; ++a) {
        const int row = a >> 1, kT = a & 1;
        const int nIdx = idx_s[row][kT * 16 + l15];
        bf16x8 Bh[KS], Bl[KS];
        #pragma unroll
        for (int s = 0; s < KS; ++s) {
            const size_t off = (size_t)nIdx * D + 32 * s + 8 * l4;
            Bh[s] = *reinterpret_cast<const bf16x8*>(Xhi + off);
            Bl[s] = *reinterpret_cast<const bf16x8*>(Xlo + off);
        }
        f32x4 Ca = {0,0,0,0}, Cb = {0,0,0,0}, Cc = {0,0,0,0};
        #pragma unroll
        for (int s = 0; s < KS; ++s) {
            Ca = __builtin_amdgcn_mfma_f32_16x16x32_bf16(Ahi[s], Bh[s], Ca, 0, 0, 0);
            Cb = __builtin_amdgcn_mfma_f32_16x16x32_bf16(Ahi[s], Bl[s], Cb, 0, 0, 0);
            Cc = __builtin_amdgcn_mfma_f32_16x16x32_bf16(Alo[s], Bh[s], Cc, 0, 0, 0);
        }
        float ps[4];
        #pragma unroll
        for (int r = 0; r < 4; ++r) {
            const float h = (Ca[r] + Cb[r]) + Cc[r]
                          + hself_s[row][waveU * 16 + 4 * l4 + r];
            ps[r] = fminf(1.f, fmaxf(-1.f, h));
        }
        #pragma unroll
        for (int off = 1; off <= 8; off <<= 1)
            #pragma unroll
            for (int r = 0; r < 4; ++r)
                ps[r] += __shfl_xor(ps[r], off);
        if (l15 == 0)
            #pragma unroll
            for (int r = 0; r < 4; ++r)
                part[row][kT][waveU * 16 + 4 * l4 + r] = ps[r] * (1.f / KNN);
    }
    __syncthreads();

    {
        const int og   = t / SPL2;
        const int spl  = t % SPL2;
        const int orow = og >> 6, o = og & 63;
        const int c0   = spl * CL;
        float s = 0.f;
        for (int c4 = 0; c4 < CL / 4; ++c4) {
            const int c = c0 + 4 * c4;
            const float4 w = *reinterpret_cast<const float4*>(W2 + (size_t)o * W2C + c);
            float vs[4];
            if (c < HDIM) {
                const float4 q0 = *reinterpret_cast<const float4*>(&part[orow][0][c]);
                const float4 q1 = *reinterpret_cast<const float4*>(&part[orow][1][c]);
                vs[0] = q0.x + q1.x; vs[1] = q0.y + q1.y;
                vs[2] = q0.z + q1.z; vs[3] = q0.w + q1.w;
            } else {
                const float4 xv = *reinterpret_cast<const float4*>(&xi[orow][c - HDIM]);
                vs[0] = xv.x; vs[1] = xv.y; vs[2] = xv.z; vs[3] = xv.w;
            }
            const float wv[4] = {w.x, w.y, w.z, w.w};
            #pragma unroll
            for (int j = 0; j < 4; ++j)
                s = fmaf(vs[j], wv[j], s);
        }
        #pragma unroll
        for (int off = SPL2 / 2; off; off >>= 1) s += __shfl_down(s, off);
        if (spl == 0) {
            if (LAYER == 0)
                out[(size_t)(rowBase + orow) * 128 + 64 + o] = s;
            else
                out[(size_t)(rowBase + orow) * ODIM + o] = s;
        }
    }
    if (LAYER == 0 && t < RPB * 64) {
        const int orow = t >> 6, d = t & 63;
        out[(size_t)(rowBase + orow) * 128 + d] = xi[orow][d];
    }
}

extern "C" void kernel_launch(void* const* d_in, const int* in_sizes, int n_in,
                              void* d_out, int out_size, void* d_ws, size_t ws_size,
                              hipStream_t stream) {
    const float* x    = (const float*)d_in[0];
    const float* w0   = (const float*)d_in[1];
    const float* w2_0 = (const float*)d_in[2];
    const float* w1   = (const float*)d_in[3];
    const float* w2_1 = (const float*)d_in[4];
    float* out = (float*)d_out;

    char* ws = (char*)d_ws;
    float* sq  = (float*)ws;
    int*   idx = (int*)(ws + (size_t)NP * 4);
    float* x1  = (float*)(ws + (size_t)NP * 4 + (size_t)NP * KNN * 4);
    unsigned short* xhi = (unsigned short*)(ws + (size_t)NP * 4
                          + (size_t)NP * KNN * 4 + (size_t)NP * HDIM * 4);
    unsigned short* xlo = xhi + (size_t)NP * HDIM;
    unsigned short* wa0hi = xlo + (size_t)NP * HDIM;
    unsigned short* wa0lo = wa0hi + HDIM * 64;
    unsigned short* wa1hi = wa0lo + HDIM * 64;
    unsigned short* wa1lo = wa1hi + HDIM * 128;

    wsplit_kernel<<<(HDIM * 64 + 255) / 256, 256, 0, stream>>>(w0, wa0hi, wa0lo, 64);
    wsplit_kernel<<<(HDIM * 128 + 255) / 256, 256, 0, stream>>>(w1, wa1hi, wa1lo, 128);

    // layer 0 (D = 64)
    splitsq_kernel<64><<<NP / 4, 256, 0, stream>>>(x, xhi, xlo, sq);
    topk_kernel<64><<<NP / 32, 512, 0, stream>>>(xhi, xlo, sq, idx);
    mlp_kernel<64, 0><<<NP / 2, 512, 0, stream>>>(x, xhi, xlo, wa0hi, wa0lo,
                                                  w0, w2_0, idx, x1);

    // layer 1 (D = 128, x1 = [x, o0])
    splitsq_kernel<128><<<NP / 4, 256, 0, stream>>>(x1, xhi, xlo, sq);
    topk_kernel<128><<<NP / 32, 512, 0, stream>>>(xhi, xlo, sq, idx);
    mlp_kernel<128, 1><<<NP / 2, 512, 0, stream>>>(x1, xhi, xlo, wa1hi, wa1lo,
                                                   w1, w2_1, idx, out);
}